// Round 6
// baseline (207.281 us; speedup 1.0000x reference)
//
#include <hip/hip_runtime.h>
#include <math.h>

#define N 2048
#define E 65536
#define EMBED 64
#define H 128
#define NT 20
#define C3 320   /* EMBED + H + H */
#define CAP 96   /* bucket capacity; Poisson(32) degrees, max ~60 */
#define SLOPE 0.01f
#define NBLK 256
#define NTHR 512

__device__ __forceinline__ float leaky(float x) { return x > 0.f ? x : SLOPE * x; }

__device__ __forceinline__ float wave_sum(float v) {
#pragma unroll
    for (int o = 32; o > 0; o >>= 1) v += __shfl_xor(v, o, 64);
    return v;
}

// Two-level grid barrier for 256 co-resident blocks (1 block/CU exactly).
// Level 1: 8 arrival lines (32 blocks each, parallel RMW streams at LLC).
// Level 2: the ticket-(32*phase-1) arriver of each line promotes one RMW to a
// single root counter; all blocks poll ONLY the root (one load per sweep).
// Monotonic counters across phases -> no reset. Release fence (L2 writeback)
// precedes arrival; acquire fence (L1/L2 inv) follows detection -> cross-XCD
// producer/consumer is safe despite non-coherent per-XCD L2s.
__device__ __forceinline__ void grid_sync(int* lines, int* root, int phase, int b) {
    __syncthreads();
    if (threadIdx.x == 0) {
        __builtin_amdgcn_fence(__ATOMIC_RELEASE, "agent");
        int t = __hip_atomic_fetch_add(&lines[(b & 7) << 6], 1, __ATOMIC_RELAXED,
                                       __HIP_MEMORY_SCOPE_AGENT);
        if (t == 32 * phase - 1)
            __hip_atomic_fetch_add(root, 1, __ATOMIC_RELAXED, __HIP_MEMORY_SCOPE_AGENT);
        while (__hip_atomic_load(root, __ATOMIC_RELAXED, __HIP_MEMORY_SCOPE_AGENT) < 8 * phase)
            __builtin_amdgcn_s_sleep(16);
        __builtin_amdgcn_fence(__ATOMIC_ACQUIRE, "agent");
    }
    __syncthreads();
}

// ====== gate: one wave, one dst, 16-edge batches ======
__device__ __forceinline__ void gate_wave16(
    int base, int lane, float xr,
    const float* __restrict__ A,
    float w0, float w1, float attl0, float attl1,
    const int2* __restrict__ se, int cnt,
    float& out0, float& out1) {
    int c0 = 2 * lane;
    float mmax = -INFINITY, s = 0.f, v0 = 0.f, v1 = 0.f;
    for (int i0 = 0; i0 < cnt; i0 += 16) {
        int nb = cnt - i0; if (nb > 16) nb = 16;
        float h0[16], h1v[16], p[16];
#pragma unroll
        for (int e = 0; e < 16; e++) {
            float ea = 0.f; float2 av = make_float2(0.f, 0.f);
            if (e < nb) {
                int2 v = se[base + i0 + e];
                ea = __int_as_float(v.y);
                av = *(const float2*)&A[v.x * H + c0];
            }
            h0[e] = leaky(fmaf(w0, ea, av.x));
            h1v[e] = leaky(fmaf(w1, ea, av.y));
            p[e] = h0[e] * attl0 + h1v[e] * attl1;
        }
        // 16 independent butterflies
#pragma unroll
        for (int o = 32; o > 0; o >>= 1) {
#pragma unroll
            for (int e = 0; e < 16; e++) p[e] += __shfl_xor(p[e], o, 64);
        }
        float alpha[16];
#pragma unroll
        for (int e = 0; e < 16; e++)
            alpha[e] = (e < nb) ? leaky(p[e] + xr) : -INFINITY;
        float mb = alpha[0];
#pragma unroll
        for (int e = 1; e < 16; e++) mb = fmaxf(mb, alpha[e]);
        float mnew = fmaxf(mmax, mb);
        float scale = __expf(mmax - mnew);  // first batch: exp(-inf)=0
        float sw = 0.f, sv0 = 0.f, sv1 = 0.f;
#pragma unroll
        for (int e = 0; e < 16; e++) {
            float we = __expf(alpha[e] - mnew);  // invalid lanes -> 0
            sw += we;
            sv0 = fmaf(we, h0[e], sv0);
            sv1 = fmaf(we, h1v[e], sv1);
        }
        s = fmaf(s, scale, sw);
        v0 = fmaf(v0, scale, sv0);
        v1 = fmaf(v1, scale, sv1);
        mmax = mnew;
    }
    float inv = 1.f / (s + 1e-16f);
    out0 = v0 * inv;
    out1 = v1 * inv;
}

// ===== fused kernel: 256 blocks x 512 threads (1 block/CU), 3 grid barriers =====
__global__ __launch_bounds__(NTHR) void k_fused(
    const int* __restrict__ ids, const int* __restrict__ ei,
    const float* __restrict__ eattr, const float* __restrict__ mmat,
    const float* __restrict__ emb,
    const float* __restrict__ l0_lin1, const float* __restrict__ l0_lin2,
    const float* __restrict__ l0_att_l, const float* __restrict__ l0_att_r,
    const float* __restrict__ l0_bias,
    const float* __restrict__ l1_lin1, const float* __restrict__ l1_lin2,
    const float* __restrict__ l1_att_l, const float* __restrict__ l1_att_r,
    const float* __restrict__ l1_bias,
    const float* __restrict__ W1, const float* __restrict__ b1,
    const float* __restrict__ W2, const float* __restrict__ b2,
    int* __restrict__ cursor, int* __restrict__ bar, int* __restrict__ root,
    int2* __restrict__ se,
    float* __restrict__ A0, float* __restrict__ A1,
    float* __restrict__ bT,
    float* __restrict__ WT1, float* __restrict__ LT0, float* __restrict__ LT1,
    float* __restrict__ out) {
    // LDS (floats): xL[8][64] | agg[8][128] | hs[8][128] | feat[8][320] |
    //               aL[8][20] | Lrow[8][2048] | redM[64] | redS[64]
    __shared__ float smem[512 + 1024 + 1024 + 2560 + 160 + 16384 + 64 + 64];
    float* xL   = smem;                  // 512
    float* agg  = smem + 512;            // 1024
    float* hs   = smem + 1536;           // 1024
    float* feat = smem + 2560;           // 2560
    float* aL   = smem + 5120;           // 160
    float* Lrow = smem + 5280;           // 16384
    float* redM = smem + 21664;          // 64
    float* redS = smem + 21728;          // 64
    const int b = blockIdx.x;
    const int tid = threadIdx.x;
    const int n0 = b * 8;

    // ------- P0 (balanced): scatter 256 edges + transpose slice + xL + A0 -------
    if (tid < 256) {                      // scatter: every block does 256 edges
        int e = b * 256 + tid;
        int d = ei[E + e];
        int pos = atomicAdd(&cursor[d], 1);
        if (pos < CAP)
            se[d * CAP + pos] = make_int2(ei[e], __float_as_int(eattr[e]));
    } else {                              // transpose slice (49152 total)
        int j = b * 256 + (tid - 256);
        if (j < 16384) {                  // WT1 = l1_lin1[:, :H]^T
            WT1[j] = l1_lin1[(j & 127) * (H + 1) + (j >> 7)];
        } else if (j < 32768) {           // LT0 = l0_lin2^T
            int jj = j - 16384;
            LT0[jj] = l0_lin2[(jj & 127) * H + (jj >> 7)];
        } else if (j < 49152) {           // LT1 = l1_lin2^T
            int jj = j - 32768;
            LT1[jj] = l1_lin2[(jj & 127) * H + (jj >> 7)];
        }
    }
    {   // xL: one element per thread (8 nodes x 64 ch == 512)
        int g = tid >> 6, c = tid & 63;
        xL[g * EMBED + c] = emb[ids[n0 + g] * EMBED + c];
    }
    __syncthreads();
    {   // lin0: A0 rows for this block's 8 nodes; 2 outputs/thread
        int k = tid & 127, q = tid >> 7;  // q 0..3 -> nodes q, q+4
        const float* wr = l0_lin1 + k * (EMBED + 1);
        float accA = 0.f, accB = 0.f;
#pragma unroll 4
        for (int c = 0; c < EMBED; c++) {
            float w = wr[c];
            accA = fmaf(xL[q * EMBED + c], w, accA);
            accB = fmaf(xL[(q + 4) * EMBED + c], w, accB);
        }
        A0[(n0 + q) * H + k] = accA;
        A0[(n0 + q + 4) * H + k] = accB;
    }
    grid_sync(bar, root, 1, b);

    // ---------------- P1: gate0 (8 dsts, 1 wave/dst, batch-16) + lin1 + A1 ----------------
    {
        int wv = __builtin_amdgcn_readfirstlane(tid >> 6);  // 0..7
        int lane = tid & 63;
        int c0 = 2 * lane;
        int dst = n0 + wv;

        float xr = wave_sum(xL[wv * EMBED + lane] * l0_att_r[lane]);
        float attl0 = l0_att_l[c0], attl1 = l0_att_l[c0 + 1];
        float w0 = l0_lin1[c0 * (EMBED + 1) + EMBED];
        float w1 = l0_lin1[(c0 + 1) * (EMBED + 1) + EMBED];
        int cnt = cursor[dst]; if (cnt > CAP) cnt = CAP;

        float o0, o1;
        gate_wave16(dst * CAP, lane, xr, A0, w0, w1, attl0, attl1, se, cnt, o0, o1);
        agg[wv * H + c0] = o0;
        agg[wv * H + c0 + 1] = o1;
        __syncthreads();

        // h1 = relu(agg @ LT0 + b0): 2 outputs/thread -> hs (LDS only)
        int k = tid & 127, q = tid >> 7;
        float bk = l0_bias[k];
        float acc0 = bk, acc1 = bk;
#pragma unroll 2
        for (int ct = 0; ct < H / 4; ct++) {
            float u0 = LT0[(4 * ct + 0) * H + k];
            float u1 = LT0[(4 * ct + 1) * H + k];
            float u2 = LT0[(4 * ct + 2) * H + k];
            float u3 = LT0[(4 * ct + 3) * H + k];
            float4 f0 = *(const float4*)&agg[q * H + 4 * ct];
            float4 f1 = *(const float4*)&agg[(q + 4) * H + 4 * ct];
            acc0 = fmaf(f0.x, u0, acc0); acc0 = fmaf(f0.y, u1, acc0);
            acc0 = fmaf(f0.z, u2, acc0); acc0 = fmaf(f0.w, u3, acc0);
            acc1 = fmaf(f1.x, u0, acc1); acc1 = fmaf(f1.y, u1, acc1);
            acc1 = fmaf(f1.z, u2, acc1); acc1 = fmaf(f1.w, u3, acc1);
        }
        hs[q * H + k] = fmaxf(acc0, 0.f);
        hs[(q + 4) * H + k] = fmaxf(acc1, 0.f);
        __syncthreads();

        // A1 = h1 @ WT1 (cross-block operand -> global)
        float a0 = 0.f, a1 = 0.f;
#pragma unroll 2
        for (int ct = 0; ct < H / 4; ct++) {
            float u0 = WT1[(4 * ct + 0) * H + k];
            float u1 = WT1[(4 * ct + 1) * H + k];
            float u2 = WT1[(4 * ct + 2) * H + k];
            float u3 = WT1[(4 * ct + 3) * H + k];
            float4 f0 = *(const float4*)&hs[q * H + 4 * ct];
            float4 f1 = *(const float4*)&hs[(q + 4) * H + 4 * ct];
            a0 = fmaf(f0.x, u0, a0); a0 = fmaf(f0.y, u1, a0);
            a0 = fmaf(f0.z, u2, a0); a0 = fmaf(f0.w, u3, a0);
            a1 = fmaf(f1.x, u0, a1); a1 = fmaf(f1.y, u1, a1);
            a1 = fmaf(f1.z, u2, a1); a1 = fmaf(f1.w, u3, a1);
        }
        A1[(n0 + q) * H + k] = a0;
        A1[(n0 + q + 4) * H + k] = a1;
    }
    grid_sync(bar, root, 2, b);

    // ---------------- P2: gate1 (batch-16) + h2 + tail ----------------
    {
        int wv = __builtin_amdgcn_readfirstlane(tid >> 6);
        int lane = tid & 63;
        int c0 = 2 * lane;
        int dst = n0 + wv;

        float xr = wave_sum(hs[wv * H + lane] * l1_att_r[lane] +
                            hs[wv * H + 64 + lane] * l1_att_r[64 + lane]);
        float attl0 = l1_att_l[c0], attl1 = l1_att_l[c0 + 1];
        float w0 = l1_lin1[c0 * (H + 1) + H];
        float w1 = l1_lin1[(c0 + 1) * (H + 1) + H];
        int cnt = cursor[dst]; if (cnt > CAP) cnt = CAP;

        float o0, o1;
        gate_wave16(dst * CAP, lane, xr, A1, w0, w1, attl0, attl1, se, cnt, o0, o1);
        agg[wv * H + c0] = o0;
        agg[wv * H + c0 + 1] = o1;

        // feat = [x | h1 | h2]
        for (int idx = tid; idx < 8 * EMBED; idx += NTHR) {
            int g = idx >> 6, c = idx & 63;
            feat[g * C3 + c] = xL[g * EMBED + c];
        }
        for (int idx = tid; idx < 8 * H; idx += NTHR) {
            int g = idx >> 7, c = idx & 127;
            feat[g * C3 + EMBED + c] = hs[g * H + c];
        }
        __syncthreads();

        // h2 = relu(agg @ LT1 + bL1): 2 outputs/thread
        int k = tid & 127, q = tid >> 7;
        float bk = l1_bias[k];
        float acc0 = bk, acc1 = bk;
#pragma unroll 2
        for (int ct = 0; ct < H / 4; ct++) {
            float u0 = LT1[(4 * ct + 0) * H + k];
            float u1 = LT1[(4 * ct + 1) * H + k];
            float u2 = LT1[(4 * ct + 2) * H + k];
            float u3 = LT1[(4 * ct + 3) * H + k];
            float4 f0 = *(const float4*)&agg[q * H + 4 * ct];
            float4 f1 = *(const float4*)&agg[(q + 4) * H + 4 * ct];
            acc0 = fmaf(f0.x, u0, acc0); acc0 = fmaf(f0.y, u1, acc0);
            acc0 = fmaf(f0.z, u2, acc0); acc0 = fmaf(f0.w, u3, acc0);
            acc1 = fmaf(f1.x, u0, acc1); acc1 = fmaf(f1.y, u1, acc1);
            acc1 = fmaf(f1.z, u2, acc1); acc1 = fmaf(f1.w, u3, acc1);
        }
        feat[q * C3 + EMBED + H + k] = fmaxf(acc0, 0.f);
        feat[(q + 4) * C3 + EMBED + H + k] = fmaxf(acc1, 0.f);
        __syncthreads();

        // 320 tail outputs: a-side -> LDS aL (b1 folded in), b-side -> global bT
        if (tid < 320) {
            int g = tid / 40, u = tid % 40;
            int t = u % 20, side = u / 20;
            const float* wrow = W1 + t * (2 * C3) + side * C3;
            float s = 0.f;
#pragma unroll 4
            for (int ct = 0; ct < C3 / 4; ct++) {
                float4 fv = *(const float4*)&feat[g * C3 + 4 * ct];
                float4 wv4 = *(const float4*)&wrow[4 * ct];
                s = fmaf(fv.x, wv4.x, s);
                s = fmaf(fv.y, wv4.y, s);
                s = fmaf(fv.z, wv4.z, s);
                s = fmaf(fv.w, wv4.w, s);
            }
            if (side == 0) aL[g * NT + t] = s + b1[t];
            else bT[t * N + (n0 + g)] = s;
        }
    }
    grid_sync(bar, root, 3, b);

    // ------- P3: logits via LDS staging + row softmax (8 rows/block) -------
    {
        int lane = tid & 63, wv = tid >> 6;  // wv 0..7
        int j = 4 * tid;                     // 512 threads x 4 = 2048 cols
        float w2r[NT];
#pragma unroll
        for (int t = 0; t < NT; t++) w2r[t] = W2[t];
        float b2v = b2[0];
        float4 bt4[NT];
#pragma unroll
        for (int t = 0; t < NT; t++) bt4[t] = *(const float4*)&bT[t * N + j];

        // pass 1: logits -> Lrow; per-row max partials -> redM
#pragma unroll
        for (int g = 0; g < 8; g++) {
            float4 s4 = make_float4(b2v, b2v, b2v, b2v);
#pragma unroll
            for (int t = 0; t < NT; t++) {
                float a = aL[g * NT + t];
                float w = w2r[t];
                s4.x = fmaf(fmaxf(a + bt4[t].x, 0.f), w, s4.x);
                s4.y = fmaf(fmaxf(a + bt4[t].y, 0.f), w, s4.y);
                s4.z = fmaf(fmaxf(a + bt4[t].z, 0.f), w, s4.z);
                s4.w = fmaf(fmaxf(a + bt4[t].w, 0.f), w, s4.w);
            }
            float4 mm = *(const float4*)&mmat[(size_t)(n0 + g) * N + j];
            s4.x *= mm.x; s4.y *= mm.y; s4.z *= mm.z; s4.w *= mm.w;
            *(float4*)&Lrow[g * 2048 + j] = s4;
            float tm = fmaxf(fmaxf(s4.x, s4.y), fmaxf(s4.z, s4.w));
#pragma unroll
            for (int o = 32; o > 0; o >>= 1) tm = fmaxf(tm, __shfl_xor(tm, o, 64));
            if (lane == 0) redM[g * 8 + wv] = tm;
        }
        __syncthreads();
        float mfin[8];
#pragma unroll
        for (int g = 0; g < 8; g++) {
            float m = redM[g * 8 + 0];
#pragma unroll
            for (int w = 1; w < 8; w++) m = fmaxf(m, redM[g * 8 + w]);
            mfin[g] = m;
        }
        // pass 2: exp in place -> Lrow; sum partials -> redS
#pragma unroll
        for (int g = 0; g < 8; g++) {
            float4 v = *(const float4*)&Lrow[g * 2048 + j];
            v.x = __expf(v.x - mfin[g]);
            v.y = __expf(v.y - mfin[g]);
            v.z = __expf(v.z - mfin[g]);
            v.w = __expf(v.w - mfin[g]);
            *(float4*)&Lrow[g * 2048 + j] = v;
            float ts = v.x + v.y + v.z + v.w;
#pragma unroll
            for (int o = 32; o > 0; o >>= 1) ts += __shfl_xor(ts, o, 64);
            if (lane == 0) redS[g * 8 + wv] = ts;
        }
        __syncthreads();
        // pass 3: normalize + write
#pragma unroll
        for (int g = 0; g < 8; g++) {
            float s = 0.f;
#pragma unroll
            for (int w = 0; w < 8; w++) s += redS[g * 8 + w];
            float inv = 1.f / s;
            float4 v = *(const float4*)&Lrow[g * 2048 + j];
            v.x *= inv; v.y *= inv; v.z *= inv; v.w *= inv;
            *(float4*)&out[(size_t)(n0 + g) * N + j] = v;
        }
    }
}

extern "C" void kernel_launch(void* const* d_in, const int* in_sizes, int n_in,
                              void* d_out, int out_size, void* d_ws, size_t ws_size,
                              hipStream_t stream) {
    const int*   node_ids = (const int*)d_in[0];
    const int*   ei       = (const int*)d_in[1];   // [2][E]: row0 = src, row1 = dst
    const float* eattr    = (const float*)d_in[2];
    const float* mmat     = (const float*)d_in[3];
    const float* emb      = (const float*)d_in[4];
    const float* l0_lin1  = (const float*)d_in[5];
    const float* l0_lin2  = (const float*)d_in[6];
    const float* l0_att_l = (const float*)d_in[7];
    const float* l0_att_r = (const float*)d_in[8];
    const float* l0_bias  = (const float*)d_in[9];
    const float* l1_lin1  = (const float*)d_in[10];
    const float* l1_lin2  = (const float*)d_in[11];
    const float* l1_att_l = (const float*)d_in[12];
    const float* l1_att_r = (const float*)d_in[13];
    const float* l1_bias  = (const float*)d_in[14];
    const float* W1       = (const float*)d_in[15];
    const float* b1       = (const float*)d_in[16];
    const float* W2       = (const float*)d_in[17];
    const float* b2       = (const float*)d_in[18];
    float* out = (float*)d_out;

    char* w = (char*)d_ws;
    auto alloc = [&](size_t bytes) {
        char* p = w;
        w += (bytes + 255) & ~(size_t)255;
        return p;
    };
    int*   cursor = (int*)alloc((N + 640) * sizeof(int));  // cursor | 8 lines | root
    int*   bar    = cursor + N;          // 512 ints (8 lines x 64-int stride)
    int*   root   = bar + 512;           // own cache line
    int2*  se     = (int2*)alloc(N * CAP * sizeof(int2));
    float* A0     = (float*)alloc(N * H * sizeof(float));
    float* A1     = (float*)alloc(N * H * sizeof(float));
    float* bT     = (float*)alloc(NT * N * sizeof(float));
    float* WT1    = (float*)alloc(H * H * sizeof(float));
    float* LT0    = (float*)alloc(H * H * sizeof(float));
    float* LT1    = (float*)alloc(H * H * sizeof(float));

    hipMemsetAsync(cursor, 0, (N + 640) * sizeof(int), stream);

    k_fused<<<NBLK, NTHR, 0, stream>>>(node_ids, ei, eattr, mmat, emb,
                                       l0_lin1, l0_lin2, l0_att_l, l0_att_r, l0_bias,
                                       l1_lin1, l1_lin2, l1_att_l, l1_att_r, l1_bias,
                                       W1, b1, W2, b2,
                                       cursor, bar, root, se, A0, A1,
                                       bT, WT1, LT0, LT1, out);
}

// Round 7
// 187.130 us; speedup vs baseline: 1.1077x; 1.1077x over previous
//
#include <hip/hip_runtime.h>
#include <math.h>

#define N 2048
#define E 65536
#define EMBED 64
#define H 128
#define NT 20
#define C3 320   /* EMBED + H + H */
#define CAP 96   /* bucket capacity; Poisson(32) degrees, max ~60 */
#define SLOPE 0.01f

__device__ __forceinline__ float leaky(float x) { return x > 0.f ? x : SLOPE * x; }

__device__ __forceinline__ float wave_sum(float v) {
#pragma unroll
    for (int o = 32; o > 0; o >>= 1) v += __shfl_xor(v, o, 64);
    return v;
}

// =============== prep: scatter + weight transposes + x-gather + A0 ===============
__global__ __launch_bounds__(256) void k_prep(
    const int* __restrict__ ei, const float* __restrict__ eattr,
    int* __restrict__ cursor, int* __restrict__ srcs, float* __restrict__ eas,
    const float* __restrict__ l1_lin1, float* __restrict__ WT1,
    const float* __restrict__ l0_lin2, float* __restrict__ LT0,
    const float* __restrict__ l1_lin2, float* __restrict__ LT1,
    const int* __restrict__ ids, const float* __restrict__ emb,
    const float* __restrict__ l0_lin1,
    float* __restrict__ x, float* __restrict__ A) {
    int b = blockIdx.x;
    int tid = threadIdx.x;
    if (b < 256) {                       // ---- scatter ----
        int e = b * 256 + tid;
        int d = ei[E + e];
        int pos = atomicAdd(&cursor[d], 1);
        if (pos < CAP) {
            srcs[d * CAP + pos] = ei[e];
            eas[d * CAP + pos] = eattr[e];
        }
    } else if (b < 448) {                // ---- transposes ----
        int j = (b - 256) * 256 + tid;
        if (j < 16384) {
            int c = j >> 7, k = j & 127;
            WT1[j] = l1_lin1[k * (H + 1) + c];
        } else if (j < 32768) {
            int jj = j - 16384; int c = jj >> 7, k = jj & 127;
            LT0[jj] = l0_lin2[k * H + c];
        } else {
            int jj = j - 32768; int c = jj >> 7, k = jj & 127;
            LT1[jj] = l1_lin2[k * H + c];
        }
    } else {                             // ---- lin0: 8 nodes/block ----
        __shared__ float lw[EMBED][130];
        int n0 = (b - 448) * 8;
        for (int j = tid; j < H * (EMBED + 1); j += 256) {
            int k = j / (EMBED + 1), c = j % (EMBED + 1);
            float v = l0_lin1[j];
            if (c < EMBED) lw[c][k] = v;
        }
        for (int idx = tid; idx < 8 * EMBED; idx += 256) {
            int g = idx >> 6, c = idx & 63;
            x[(n0 + g) * EMBED + c] = emb[ids[n0 + g] * EMBED + c];
        }
        __syncthreads();
        int k = tid & 127, half = tid >> 7;
        const float* xr[4];
#pragma unroll
        for (int it = 0; it < 4; it++) {
            int nn = __builtin_amdgcn_readfirstlane(n0 + 2 * it + half);
            xr[it] = emb + (size_t)ids[nn] * EMBED;
        }
        float acc[4] = {0.f, 0.f, 0.f, 0.f};
#pragma unroll 4
        for (int c = 0; c < EMBED; c++) {
            float wt = lw[c][k];
#pragma unroll
            for (int it = 0; it < 4; it++) acc[it] = fmaf(xr[it][c], wt, acc[it]);
        }
#pragma unroll
        for (int it = 0; it < 4; it++) A[(n0 + 2 * it + half) * H + k] = acc[it];
    }
}

// =============== shared gate device function: one wave, one dst, batched edges ===============
__device__ __forceinline__ void gate_wave(
    int dst, int lane, float xr,
    const float* __restrict__ A,
    float w0, float w1, float attl0, float attl1,
    const int* __restrict__ srcs, const float* __restrict__ eas, int cnt,
    float& out0, float& out1) {
    int c0 = 2 * lane;
    int base = dst * CAP;
    float mmax = -INFINITY, s = 0.f, v0 = 0.f, v1 = 0.f;
    for (int i0 = 0; i0 < cnt; i0 += 8) {
        int nb = cnt - i0; if (nb > 8) nb = 8;
        float h0[8], h1[8], p[8];
#pragma unroll
        for (int e = 0; e < 8; e++) {
            float ea = 0.f; float2 av = make_float2(0.f, 0.f);
            if (e < nb) {
                int sn = srcs[base + i0 + e];
                ea = eas[base + i0 + e];
                av = *(const float2*)&A[sn * H + c0];
            }
            h0[e] = leaky(fmaf(w0, ea, av.x));
            h1[e] = leaky(fmaf(w1, ea, av.y));
            p[e] = h0[e] * attl0 + h1[e] * attl1;
        }
        // 8 independent butterflies (pipelined shuffles)
#pragma unroll
        for (int o = 32; o > 0; o >>= 1) {
#pragma unroll
            for (int e = 0; e < 8; e++) p[e] += __shfl_xor(p[e], o, 64);
        }
        float alpha[8];
#pragma unroll
        for (int e = 0; e < 8; e++)
            alpha[e] = (e < nb) ? leaky(p[e] + xr) : -INFINITY;
        float mb = alpha[0];
#pragma unroll
        for (int e = 1; e < 8; e++) mb = fmaxf(mb, alpha[e]);
        float mnew = fmaxf(mmax, mb);
        float scale = __expf(mmax - mnew);  // first batch: exp(-inf)=0
        float sw = 0.f, sv0 = 0.f, sv1 = 0.f;
#pragma unroll
        for (int e = 0; e < 8; e++) {
            float we = __expf(alpha[e] - mnew);  // invalid lanes -> 0
            sw += we;
            sv0 = fmaf(we, h0[e], sv0);
            sv1 = fmaf(we, h1[e], sv1);
        }
        s = fmaf(s, scale, sw);
        v0 = fmaf(v0, scale, sv0);
        v1 = fmaf(v1, scale, sv1);
        mmax = mnew;
    }
    float inv = 1.f / (s + 1e-16f);
    out0 = v0 * inv;
    out1 = v1 * inv;
}

// =============== gate0 + lin1 fused: 8 dsts/block, 512 threads ===============
__global__ __launch_bounds__(512) void k_g0(
    const float* __restrict__ x, const float* __restrict__ A0,
    const float* __restrict__ l0_lin1,
    const float* __restrict__ att_l, const float* __restrict__ att_r,
    const int* __restrict__ srcs, const float* __restrict__ eas,
    const int* __restrict__ cursor,
    const float* __restrict__ LT0, const float* __restrict__ b0,
    const float* __restrict__ WT1,
    float* __restrict__ h1, float* __restrict__ A1) {
    __shared__ float agg_s[8][H];
    __shared__ float hs[8][H];
    int n0 = blockIdx.x * 8;
    int tid = threadIdx.x;
    int wv = __builtin_amdgcn_readfirstlane(tid >> 6);  // 0..7
    int lane = tid & 63;
    int c0 = 2 * lane;

    int dst = n0 + wv;
    float xr = wave_sum(x[dst * EMBED + lane] * att_r[lane]);
    float attl0 = att_l[c0], attl1 = att_l[c0 + 1];
    float w0 = l0_lin1[c0 * (EMBED + 1) + EMBED];
    float w1 = l0_lin1[(c0 + 1) * (EMBED + 1) + EMBED];
    int cnt = cursor[dst]; if (cnt > CAP) cnt = CAP;

    float o0, o1;
    gate_wave(dst, lane, xr, A0, w0, w1, attl0, attl1, srcs, eas, cnt, o0, o1);
    agg_s[wv][c0] = o0;
    agg_s[wv][c0 + 1] = o1;
    __syncthreads();

    // h1 = relu(agg @ LT0 + b0); two nodes per thread-group (q, q+4); float4 LDS reads
    int k = tid & 127, q = tid >> 7;  // q in 0..3
    float bk = b0[k];
    float acc0 = bk, acc1 = bk;
#pragma unroll 2
    for (int ct = 0; ct < H / 4; ct++) {
        float u0 = LT0[(4 * ct + 0) * H + k];
        float u1 = LT0[(4 * ct + 1) * H + k];
        float u2 = LT0[(4 * ct + 2) * H + k];
        float u3 = LT0[(4 * ct + 3) * H + k];
        float4 f0 = *(const float4*)&agg_s[q][4 * ct];
        float4 f1 = *(const float4*)&agg_s[q + 4][4 * ct];
        acc0 = fmaf(f0.x, u0, acc0); acc0 = fmaf(f0.y, u1, acc0);
        acc0 = fmaf(f0.z, u2, acc0); acc0 = fmaf(f0.w, u3, acc0);
        acc1 = fmaf(f1.x, u0, acc1); acc1 = fmaf(f1.y, u1, acc1);
        acc1 = fmaf(f1.z, u2, acc1); acc1 = fmaf(f1.w, u3, acc1);
    }
    float hv0 = fmaxf(acc0, 0.f), hv1 = fmaxf(acc1, 0.f);
    h1[(n0 + q) * H + k] = hv0;
    h1[(n0 + q + 4) * H + k] = hv1;
    hs[q][k] = hv0;
    hs[q + 4][k] = hv1;
    __syncthreads();

    // A1 = h1 @ WT1
    float a0 = 0.f, a1 = 0.f;
#pragma unroll 2
    for (int ct = 0; ct < H / 4; ct++) {
        float u0 = WT1[(4 * ct + 0) * H + k];
        float u1 = WT1[(4 * ct + 1) * H + k];
        float u2 = WT1[(4 * ct + 2) * H + k];
        float u3 = WT1[(4 * ct + 3) * H + k];
        float4 f0 = *(const float4*)&hs[q][4 * ct];
        float4 f1 = *(const float4*)&hs[q + 4][4 * ct];
        a0 = fmaf(f0.x, u0, a0); a0 = fmaf(f0.y, u1, a0);
        a0 = fmaf(f0.z, u2, a0); a0 = fmaf(f0.w, u3, a0);
        a1 = fmaf(f1.x, u0, a1); a1 = fmaf(f1.y, u1, a1);
        a1 = fmaf(f1.z, u2, a1); a1 = fmaf(f1.w, u3, a1);
    }
    A1[(n0 + q) * H + k] = a0;
    A1[(n0 + q + 4) * H + k] = a1;
}

// =============== gate1 + tail fused: 8 dsts/block, 512 threads ===============
__global__ __launch_bounds__(512) void k_g1(
    const float* __restrict__ h1g, const float* __restrict__ A1,
    const float* __restrict__ l1_lin1,
    const float* __restrict__ att_l, const float* __restrict__ att_r,
    const int* __restrict__ srcs, const float* __restrict__ eas,
    const int* __restrict__ cursor,
    const float* __restrict__ LT1, const float* __restrict__ bL1,
    const float* __restrict__ x, const float* __restrict__ W1,
    float* __restrict__ aArr, float* __restrict__ bT) {
    __shared__ float agg_s[8][H];
    __shared__ float feat[8][C3];   // [0..63]=x, [64..191]=h1, [192..319]=h2
    int n0 = blockIdx.x * 8;
    int tid = threadIdx.x;
    int wv = __builtin_amdgcn_readfirstlane(tid >> 6);
    int lane = tid & 63;
    int c0 = 2 * lane;

    int dst = n0 + wv;
    float xr = wave_sum(h1g[dst * H + lane] * att_r[lane] +
                        h1g[dst * H + 64 + lane] * att_r[64 + lane]);
    float attl0 = att_l[c0], attl1 = att_l[c0 + 1];
    float w0 = l1_lin1[c0 * (H + 1) + H];
    float w1 = l1_lin1[(c0 + 1) * (H + 1) + H];
    int cnt = cursor[dst]; if (cnt > CAP) cnt = CAP;

    float o0, o1;
    gate_wave(dst, lane, xr, A1, w0, w1, attl0, attl1, srcs, eas, cnt, o0, o1);
    agg_s[wv][c0] = o0;
    agg_s[wv][c0 + 1] = o1;

    for (int idx = tid; idx < 8 * EMBED; idx += 512) {
        int g = idx >> 6, c = idx & 63;
        feat[g][c] = x[(n0 + g) * EMBED + c];
    }
    for (int idx = tid; idx < 8 * H; idx += 512) {
        int g = idx >> 7, c = idx & 127;
        feat[g][EMBED + c] = h1g[(n0 + g) * H + c];
    }
    __syncthreads();

    // h2 = relu(agg @ LT1 + bL1); float4 LDS reads
    int k = tid & 127, q = tid >> 7;
    float bk = bL1[k];
    float acc0 = bk, acc1 = bk;
#pragma unroll 2
    for (int ct = 0; ct < H / 4; ct++) {
        float u0 = LT1[(4 * ct + 0) * H + k];
        float u1 = LT1[(4 * ct + 1) * H + k];
        float u2 = LT1[(4 * ct + 2) * H + k];
        float u3 = LT1[(4 * ct + 3) * H + k];
        float4 f0 = *(const float4*)&agg_s[q][4 * ct];
        float4 f1 = *(const float4*)&agg_s[q + 4][4 * ct];
        acc0 = fmaf(f0.x, u0, acc0); acc0 = fmaf(f0.y, u1, acc0);
        acc0 = fmaf(f0.z, u2, acc0); acc0 = fmaf(f0.w, u3, acc0);
        acc1 = fmaf(f1.x, u0, acc1); acc1 = fmaf(f1.y, u1, acc1);
        acc1 = fmaf(f1.z, u2, acc1); acc1 = fmaf(f1.w, u3, acc1);
    }
    feat[q][EMBED + H + k] = fmaxf(acc0, 0.f);
    feat[q + 4][EMBED + H + k] = fmaxf(acc1, 0.f);
    __syncthreads();

    // 320 outputs: o = g*40 + side*20 + t
    if (tid < 320) {
        int g = tid / 40, u = tid % 40;
        int t = u % 20, side = u / 20;
        const float* wrow = W1 + t * (2 * C3) + side * C3;
        float s = 0.f;
#pragma unroll 4
        for (int ct = 0; ct < C3 / 4; ct++) {
            float4 fv = *(const float4*)&feat[g][4 * ct];
            float4 wv4 = *(const float4*)&wrow[4 * ct];
            s = fmaf(fv.x, wv4.x, s);
            s = fmaf(fv.y, wv4.y, s);
            s = fmaf(fv.z, wv4.z, s);
            s = fmaf(fv.w, wv4.w, s);
        }
        if (side == 0) aArr[(n0 + g) * NT + t] = s;
        else bT[t * N + (n0 + g)] = s;
    }
}

// =============== final: logits + row softmax, 4 rows/block, register-resident ===============
__global__ __launch_bounds__(256) void k_final(const float* __restrict__ aArr,
                                               const float* __restrict__ bT,
                                               const float* __restrict__ b1,
                                               const float* __restrict__ W2,
                                               const float* __restrict__ b2,
                                               const float* __restrict__ mmat,
                                               float* __restrict__ out) {
    __shared__ float red[16];
    int i0 = blockIdx.x * 4;
    int tid = threadIdx.x;
    int lane = tid & 63, wv = tid >> 6;
    float w2r[NT];
#pragma unroll
    for (int t = 0; t < NT; t++) w2r[t] = W2[t];
    float b2v = b2[0];
    // ab[g][t] = a_i[g][t] + b1[t], uniform across block -> scalar loads
    float ab[4][NT];
#pragma unroll
    for (int g = 0; g < 4; g++) {
#pragma unroll
        for (int t = 0; t < NT; t++)
            ab[g][t] = aArr[(i0 + g) * NT + t] + b1[t];
    }
    float l[4][8];
    float tmax[4] = {-INFINITY, -INFINITY, -INFINITY, -INFINITY};
#pragma unroll
    for (int it = 0; it < 8; it++) {
        int j = tid + 256 * it;
        float bt[NT];
#pragma unroll
        for (int t = 0; t < NT; t++) bt[t] = bT[t * N + j];
#pragma unroll
        for (int g = 0; g < 4; g++) {
            float s = b2v;
#pragma unroll
            for (int t = 0; t < NT; t++)
                s += fmaxf(ab[g][t] + bt[t], 0.f) * w2r[t];
            s *= mmat[(size_t)(i0 + g) * N + j];
            l[g][it] = s;
            tmax[g] = fmaxf(tmax[g], s);
        }
    }
#pragma unroll
    for (int g = 0; g < 4; g++) {
#pragma unroll
        for (int o = 32; o > 0; o >>= 1)
            tmax[g] = fmaxf(tmax[g], __shfl_xor(tmax[g], o, 64));
    }
    if (lane == 0) {
#pragma unroll
        for (int g = 0; g < 4; g++) red[wv * 4 + g] = tmax[g];
    }
    __syncthreads();
    float mfin[4];
#pragma unroll
    for (int g = 0; g < 4; g++)
        mfin[g] = fmaxf(fmaxf(red[g], red[4 + g]), fmaxf(red[8 + g], red[12 + g]));
    __syncthreads();

    float ts[4] = {0.f, 0.f, 0.f, 0.f};
#pragma unroll
    for (int it = 0; it < 8; it++) {
#pragma unroll
        for (int g = 0; g < 4; g++) {
            float e = __expf(l[g][it] - mfin[g]);
            l[g][it] = e;
            ts[g] += e;
        }
    }
#pragma unroll
    for (int g = 0; g < 4; g++) {
#pragma unroll
        for (int o = 32; o > 0; o >>= 1) ts[g] += __shfl_xor(ts[g], o, 64);
    }
    if (lane == 0) {
#pragma unroll
        for (int g = 0; g < 4; g++) red[wv * 4 + g] = ts[g];
    }
    __syncthreads();
    float inv[4];
#pragma unroll
    for (int g = 0; g < 4; g++)
        inv[g] = 1.f / (red[g] + red[4 + g] + red[8 + g] + red[12 + g]);

#pragma unroll
    for (int it = 0; it < 8; it++) {
        int j = tid + 256 * it;
#pragma unroll
        for (int g = 0; g < 4; g++)
            out[(size_t)(i0 + g) * N + j] = l[g][it] * inv[g];
    }
}

extern "C" void kernel_launch(void* const* d_in, const int* in_sizes, int n_in,
                              void* d_out, int out_size, void* d_ws, size_t ws_size,
                              hipStream_t stream) {
    const int*   node_ids = (const int*)d_in[0];
    const int*   ei       = (const int*)d_in[1];   // [2][E]: row0 = src, row1 = dst
    const float* eattr    = (const float*)d_in[2];
    const float* mmat     = (const float*)d_in[3];
    const float* emb      = (const float*)d_in[4];
    const float* l0_lin1  = (const float*)d_in[5];
    const float* l0_lin2  = (const float*)d_in[6];
    const float* l0_att_l = (const float*)d_in[7];
    const float* l0_att_r = (const float*)d_in[8];
    const float* l0_bias  = (const float*)d_in[9];
    const float* l1_lin1  = (const float*)d_in[10];
    const float* l1_lin2  = (const float*)d_in[11];
    const float* l1_att_l = (const float*)d_in[12];
    const float* l1_att_r = (const float*)d_in[13];
    const float* l1_bias  = (const float*)d_in[14];
    const float* W1       = (const float*)d_in[15];
    const float* b1       = (const float*)d_in[16];
    const float* W2       = (const float*)d_in[17];
    const float* b2       = (const float*)d_in[18];
    float* out = (float*)d_out;

    char* w = (char*)d_ws;
    auto alloc = [&](size_t bytes) {
        char* p = w;
        w += (bytes + 255) & ~(size_t)255;
        return p;
    };
    int*   cursor = (int*)alloc(N * sizeof(int));
    int*   srcs   = (int*)alloc(N * CAP * sizeof(int));
    float* eas    = (float*)alloc(N * CAP * sizeof(float));
    float* x      = (float*)alloc(N * EMBED * sizeof(float));
    float* A0     = (float*)alloc(N * H * sizeof(float));
    float* A1     = (float*)alloc(N * H * sizeof(float));
    float* h1     = (float*)alloc(N * H * sizeof(float));
    float* aArr   = (float*)alloc(N * NT * sizeof(float));
    float* bT     = (float*)alloc(NT * N * sizeof(float));
    float* WT1    = (float*)alloc(H * H * sizeof(float));
    float* LT0    = (float*)alloc(H * H * sizeof(float));
    float* LT1    = (float*)alloc(H * H * sizeof(float));

    hipMemsetAsync(cursor, 0, N * sizeof(int), stream);

    k_prep<<<704, 256, 0, stream>>>(ei, eattr, cursor, srcs, eas,
                                    l1_lin1, WT1, l0_lin2, LT0, l1_lin2, LT1,
                                    node_ids, emb, l0_lin1, x, A0);
    k_g0<<<N / 8, 512, 0, stream>>>(x, A0, l0_lin1, l0_att_l, l0_att_r,
                                    srcs, eas, cursor, LT0, l0_bias, WT1, h1, A1);
    k_g1<<<N / 8, 512, 0, stream>>>(h1, A1, l1_lin1, l1_att_l, l1_att_r,
                                    srcs, eas, cursor, LT1, l1_bias, x, W1, aArr, bT);
    k_final<<<N / 4, 256, 0, stream>>>(aArr, bT, b1, W2, b2, mmat, out);
}